// Round 2
// baseline (17171.652 us; speedup 1.0000x reference)
//
#include <hip/hip_runtime.h>

// ---------------------------------------------------------------------------
// Decoder: B=32, T=64, S=64, V=32000, E=H=512, L=2
// Structure:
//   prep:  cvt W_out->bf16 ; encP = enc @ W_a in FP32 (recurrence-critical!)
//   ONE persistent kernel runs all 64 steps with a HAND-ROLLED grid barrier
//   (generation barrier in workspace; graph-capture-safe, unlike
//   hipLaunchCooperativeKernel whose grid.sync state breaks under capture):
//     stage A: scores = encP . h1 ; softmax ; context      (blocks 0..31)
//     stage B: LSTM cell 0 (gates from [x_t | ctx | h0])   (units strided)
//     stage C: LSTM cell 1 (gates from [h0 | h1]) + cat    (units strided)
//   Grid: 512 blocks if occupancy query says 2 blocks/CU fit, else 256.
//   256 blocks x 256 thr are unconditionally co-resident on 256 CUs, so the
//   barrier can never deadlock. Kernel strides work by gridDim.x.
//   epilogue: out = cat @ W_out^T + b_out  (128x128 bf16 MFMA GEMM, M=2048,
//             N=32000, K=1024) ; copy h_f/c_f.
// Precision rule: anything that FEEDS BACK into the recurrence stays fp32
// (bf16 logit noise is amplified by the peaked softmax over 64 steps).
// bf16 only on the forward-only output projection (error ~0.005 << 0.12).
// ---------------------------------------------------------------------------

typedef __attribute__((ext_vector_type(8))) __bf16 bf16x8;
typedef __attribute__((ext_vector_type(4))) float f32x4;

__device__ __forceinline__ short f2b(float f) {
  unsigned u = __builtin_bit_cast(unsigned, f);
  u += 0x7fffu + ((u >> 16) & 1u);          // round-to-nearest-even
  return (short)(u >> 16);
}

__device__ __forceinline__ float wave_sum(float v) {
  for (int off = 32; off > 0; off >>= 1) v += __shfl_down(v, off);
  return v;                                  // lane 0 holds the sum
}

__device__ __forceinline__ float sigm(float x) { return 1.f / (1.f + expf(-x)); }

// Generation grid-barrier: device-scope atomics in workspace. Last arriver
// resets the count (before releasing!) and bumps the generation; everyone
// else acquire-spins on the generation. Graph-capture-safe.
__device__ __forceinline__ void gbar(unsigned* cnt, unsigned* gen) {
  __syncthreads();
  if (threadIdx.x == 0) {
    unsigned g = __hip_atomic_load(gen, __ATOMIC_RELAXED, __HIP_MEMORY_SCOPE_AGENT);
    unsigned a = __hip_atomic_fetch_add(cnt, 1u, __ATOMIC_ACQ_REL, __HIP_MEMORY_SCOPE_AGENT);
    if (a == gridDim.x - 1) {
      __hip_atomic_store(cnt, 0u, __ATOMIC_RELAXED, __HIP_MEMORY_SCOPE_AGENT);
      __hip_atomic_fetch_add(gen, 1u, __ATOMIC_RELEASE, __HIP_MEMORY_SCOPE_AGENT);
    } else {
      while (__hip_atomic_load(gen, __ATOMIC_ACQUIRE, __HIP_MEMORY_SCOPE_AGENT) == g) {
        __builtin_amdgcn_s_sleep(1);
      }
    }
  }
  __syncthreads();
}

// ---------------- converts ----------------
__global__ __launch_bounds__(256) void cvt_bf16_k(const float* __restrict__ in,
                                                  short* __restrict__ out, long n) {
  long stride = (long)gridDim.x * 256 * 4;
  for (long i = ((long)blockIdx.x * 256 + threadIdx.x) * 4; i < n; i += stride) {
    float4 v = *(const float4*)&in[i];
    short4 o; o.x = f2b(v.x); o.y = f2b(v.y); o.z = f2b(v.z); o.w = f2b(v.w);
    *(short4*)&out[i] = o;
  }
}

__global__ __launch_bounds__(256) void init_states_k(const float* __restrict__ hidden,
                                                     const float* __restrict__ cell,
                                                     float* h0, float* h1, float* c0, float* c1,
                                                     unsigned* bar) {
  int i = blockIdx.x * 256 + threadIdx.x;   // grid 64 -> 16384
  h0[i] = hidden[i]; h1[i] = hidden[16384 + i];
  c0[i] = cell[i];   c1[i] = cell[16384 + i];
  if (i == 0) { bar[0] = 0u; bar[1] = 0u; }  // barrier cnt/gen reset per replay
}

__global__ __launch_bounds__(256) void fin_states_k(const float* __restrict__ h0,
                                                    const float* __restrict__ h1,
                                                    const float* __restrict__ c0,
                                                    const float* __restrict__ c1,
                                                    float* __restrict__ out) {
  int i = blockIdx.x * 256 + threadIdx.x;   // grid 64
  out[i] = h0[i]; out[16384 + i] = h1[i];
  out[32768 + i] = c0[i]; out[49152 + i] = c1[i];
}

// ---------------- fp32 GEMM: C[MxN] = A[MxK] @ B[KxN], 64x64 tile, BK=16 ----
// Used ONLY for encP = enc @ W_a (1.07 GFLOP, one-time). FP32 because scores
// feed the softmax->recurrence loop and bf16 noise there diverges.
__global__ __launch_bounds__(256) void gemm_f32_k(
    const float* __restrict__ A, const float* __restrict__ B,
    float* __restrict__ C, int M, int N, int K, int ldb) {
  __shared__ float As[16][65];
  __shared__ float Bs[16][64];
  int tid = threadIdx.x;
  int tm = blockIdx.y * 64, tn = blockIdx.x * 64;
  int ty = tid >> 4, tx = tid & 15;
  float acc[4][4] = {};
  for (int k0 = 0; k0 < K; k0 += 16) {
    __syncthreads();
    for (int l = 0; l < 4; l++) {
      int idx = l * 256 + tid;            // 0..1023
      int m = idx >> 4, kk = idx & 15;    // A tile: 64m x 16k
      As[kk][m] = A[(long)(tm + m) * K + k0 + kk];
      int kb = idx >> 6, n = idx & 63;    // B tile: 16k x 64n (coalesced)
      Bs[kb][n] = B[(long)(k0 + kb) * ldb + tn + n];
    }
    __syncthreads();
    for (int kk = 0; kk < 16; kk++) {
      float a[4], b[4];
      for (int i = 0; i < 4; i++) a[i] = As[kk][ty * 4 + i];
      for (int j = 0; j < 4; j++) b[j] = Bs[kk][tx * 4 + j];
      for (int i = 0; i < 4; i++)
        for (int j = 0; j < 4; j++) acc[i][j] += a[i] * b[j];
    }
  }
  for (int i = 0; i < 4; i++)
    for (int j = 0; j < 4; j++)
      C[(long)(tm + ty * 4 + i) * N + tn + tx * 4 + j] = acc[i][j];
}

// ---------------- bf16 MFMA GEMM: C[MxN] = A[MxK] * Bt[NxK]^T (+bias) -------
// 128x128 tile, BK=64, 256 thr (2x2 waves of 64x64), 16x16x32 MFMA,
// global_load_lds width-16 staging, XOR-swizzled LDS (2-way max conflict).
__global__ __launch_bounds__(256) void gemm_bf16(
    const short* __restrict__ A, const short* __restrict__ Bt,
    float* __restrict__ C, const float* __restrict__ bias1,
    int M, int N, int K, int lda, int ldb, int ldc) {
  __shared__ __align__(16) short lsA[8192];
  __shared__ __align__(16) short lsB[8192];
  int tid = threadIdx.x, lane = tid & 63, w = tid >> 6;
  int wm = w >> 1, wn = w & 1;
  int tm = blockIdx.y * 128, tn = blockIdx.x * 128;
  f32x4 acc[4][4] = {};
  int kts = K >> 6;
  for (int kt = 0; kt < kts; kt++) {
    int k0 = kt << 6;
    __syncthreads();
    for (int inst = 0; inst < 4; inst++) {
      int s = w * 256 + inst * 64 + lane;
      int row = s >> 3, cc = s & 7, c = cc ^ (row & 7);
      const short* ga = A + (long)(tm + row) * lda + k0 + c * 8;
      const short* gb = Bt + (long)(tn + row) * ldb + k0 + c * 8;
      __builtin_amdgcn_global_load_lds((const __attribute__((address_space(1))) void*)ga,
                                       (__attribute__((address_space(3))) void*)&lsA[s * 8],
                                       16, 0, 0);
      __builtin_amdgcn_global_load_lds((const __attribute__((address_space(1))) void*)gb,
                                       (__attribute__((address_space(3))) void*)&lsB[s * 8],
                                       16, 0, 0);
    }
    asm volatile("s_waitcnt vmcnt(0)" ::: "memory");
    __syncthreads();
    for (int ks = 0; ks < 2; ks++) {
      bf16x8 af[4], bfr[4];
      for (int mt = 0; mt < 4; mt++) {
        int row = wm * 64 + mt * 16 + (lane & 15);
        int c = ks * 4 + (lane >> 4);
        int slot = row * 8 + (c ^ (row & 7));
        af[mt] = *(const bf16x8*)&lsA[slot * 8];
      }
      for (int nt = 0; nt < 4; nt++) {
        int row = wn * 64 + nt * 16 + (lane & 15);
        int c = ks * 4 + (lane >> 4);
        int slot = row * 8 + (c ^ (row & 7));
        bfr[nt] = *(const bf16x8*)&lsB[slot * 8];
      }
      for (int mt = 0; mt < 4; mt++)
        for (int nt = 0; nt < 4; nt++)
          acc[mt][nt] = __builtin_amdgcn_mfma_f32_16x16x32_bf16(af[mt], bfr[nt], acc[mt][nt], 0, 0, 0);
    }
  }
  for (int nt = 0; nt < 4; nt++) {
    int ccol = tn + wn * 64 + nt * 16 + (lane & 15);
    float bsum = bias1 ? bias1[ccol] : 0.f;
    for (int mt = 0; mt < 4; mt++) {
      int r0 = tm + wm * 64 + mt * 16 + ((lane >> 4) << 2);
      f32x4 v = acc[mt][nt];
      for (int r = 0; r < 4; r++)
        C[(long)(r0 + r) * ldc + ccol] = v[r] + bsum;
    }
  }
}

// ---------------- persistent recurrence: all 64 steps, 3 gbar/step ----------
// Grid-size-agnostic: stages B/C stride the 512 (b,jg) units by gridDim.x.
// LDS ~6.7KB; __launch_bounds__(256,2) caps VGPR<=256 so 2 blocks/CU fit.
__global__ __launch_bounds__(256, 2) void decode_loop_k(
    const int* __restrict__ tgt, const float* __restrict__ emb,
    const float* __restrict__ enc, const float* __restrict__ encP,
    const float* __restrict__ Wih0, const float* __restrict__ Whh0,
    const float* __restrict__ bih0, const float* __restrict__ bhh0,
    const float* __restrict__ Wih1, const float* __restrict__ Whh1,
    const float* __restrict__ bih1, const float* __restrict__ bhh1,
    float* __restrict__ ctx, float* __restrict__ st, short* __restrict__ cat,
    unsigned* __restrict__ bar) {
  __shared__ __align__(16) float sinp[1536];   // A: sh1[512] ; B: [x|ctx|h0] ; C: [h0|h1]
  __shared__ float sg[128];                    // A: sattn[64] ; B/C: gate partials
  unsigned* cnt = bar; unsigned* gen = bar + 1;
  const int g = blockIdx.x, nb = gridDim.x;
  const int tid = threadIdx.x, lane = tid & 63, w = tid >> 6;
  float* h0b = st;
  float* h1b = st + 2 * 16384;
  float* c0b = st + 4 * 16384;
  float* c1b = st + 6 * 16384;

#pragma unroll 1
  for (int t = 0; t < 64; t++) {
    const int o = (t & 1) * 16384, nn = ((t & 1) ^ 1) * 16384;

    // ---- stage A: attention (blocks 0..31, one per batch) ----
    if (g < 32) {
      const int b = g;
      const float* h1o = h1b + o;
      sinp[tid] = h1o[b * 512 + tid];
      sinp[256 + tid] = h1o[b * 512 + 256 + tid];
      __syncthreads();
      for (int i = 0; i < 16; i++) {
        int s = w * 16 + i;
        const float* ep = encP + (long)(b * 64 + s) * 512;
        float acc = 0.f;
        for (int kk = 0; kk < 2; kk++) {
          float4 ev = *(const float4*)&ep[(kk * 64 + lane) * 4];
          float4 hv = *(const float4*)&sinp[(kk * 64 + lane) * 4];
          acc += ev.x * hv.x + ev.y * hv.y + ev.z * hv.z + ev.w * hv.w;
        }
        acc = wave_sum(acc);
        if (lane == 0) sg[s] = acc;
      }
      __syncthreads();
      if (w == 0) {
        float v = sg[lane];
        float m = v;
        for (int off = 32; off > 0; off >>= 1) m = fmaxf(m, __shfl_xor(m, off));
        float e = expf(v - m);
        float ssum = e;
        for (int off = 32; off > 0; off >>= 1) ssum += __shfl_xor(ssum, off);
        sg[lane] = e / ssum;
      }
      __syncthreads();
      for (int h = tid; h < 512; h += 256) {
        float c = 0.f;
        for (int s = 0; s < 64; s++) c += sg[s] * enc[(long)(b * 64 + s) * 512 + h];
        ctx[b * 512 + h] = c;
        cat[(long)(b * 64 + t) * 1024 + 512 + h] = f2b(c);
      }
    }
    gbar(cnt, gen);

    // ---- stage B: LSTM layer 0 (512 units (b,jg), strided by grid) ----
    for (int u = g; u < 512; u += nb) {
      const int b = u >> 4, jg = u & 15;
      __syncthreads();                         // prev unit's sinp/sg reads done
      int idx = tgt[b * 64 + t];
      const float* xrow = emb + (long)idx * 512;
      for (int k = tid; k < 512; k += 256) {
        sinp[k] = (idx == 0) ? 0.f : xrow[k];  // padding_idx=0
        sinp[512 + k] = ctx[b * 512 + k];
        sinp[1024 + k] = h0b[o + b * 512 + k];
      }
      __syncthreads();
      for (int i = 0; i < 32; i++) {
        int j = w * 512 + jg * 32 + i;         // gate row (w = gate quadrant)
        const float4* w1 = (const float4*)(Wih0 + (long)j * 1024);
        const float4* w2 = (const float4*)(Whh0 + (long)j * 512);
        float acc = 0.f;
        for (int kk = 0; kk < 4; kk++) {
          float4 wv = w1[kk * 64 + lane];
          float4 iv = *(const float4*)&sinp[(kk * 64 + lane) * 4];
          acc += wv.x * iv.x + wv.y * iv.y + wv.z * iv.z + wv.w * iv.w;
        }
        for (int kk = 0; kk < 2; kk++) {
          float4 wv = w2[kk * 64 + lane];
          float4 iv = *(const float4*)&sinp[1024 + (kk * 64 + lane) * 4];
          acc += wv.x * iv.x + wv.y * iv.y + wv.z * iv.z + wv.w * iv.w;
        }
        acc = wave_sum(acc);
        if (lane == 0) sg[w * 32 + i] = acc + bih0[j] + bhh0[j];
      }
      __syncthreads();
      if (tid < 32) {
        int j2 = jg * 32 + tid;
        float ig = sg[tid], fg = sg[32 + tid], gg = sg[64 + tid], og = sg[96 + tid];
        float cold = c0b[o + b * 512 + j2];
        float cn = sigm(fg) * cold + sigm(ig) * tanhf(gg);
        float hn = sigm(og) * tanhf(cn);
        c0b[nn + b * 512 + j2] = cn;
        h0b[nn + b * 512 + j2] = hn;
      }
    }
    gbar(cnt, gen);

    // ---- stage C: LSTM layer 1 + cat write ----
    for (int u = g; u < 512; u += nb) {
      const int b = u >> 4, jg = u & 15;
      __syncthreads();
      for (int k = tid; k < 512; k += 256) {
        sinp[k] = h0b[nn + b * 512 + k];
        sinp[512 + k] = h1b[o + b * 512 + k];
      }
      __syncthreads();
      for (int i = 0; i < 32; i++) {
        int j = w * 512 + jg * 32 + i;
        const float4* w1 = (const float4*)(Wih1 + (long)j * 512);
        const float4* w2 = (const float4*)(Whh1 + (long)j * 512);
        float acc = 0.f;
        for (int kk = 0; kk < 2; kk++) {
          float4 wv = w1[kk * 64 + lane];
          float4 iv = *(const float4*)&sinp[(kk * 64 + lane) * 4];
          acc += wv.x * iv.x + wv.y * iv.y + wv.z * iv.z + wv.w * iv.w;
        }
        for (int kk = 0; kk < 2; kk++) {
          float4 wv = w2[kk * 64 + lane];
          float4 iv = *(const float4*)&sinp[512 + (kk * 64 + lane) * 4];
          acc += wv.x * iv.x + wv.y * iv.y + wv.z * iv.z + wv.w * iv.w;
        }
        acc = wave_sum(acc);
        if (lane == 0) sg[w * 32 + i] = acc + bih1[j] + bhh1[j];
      }
      __syncthreads();
      if (tid < 32) {
        int j2 = jg * 32 + tid;
        float ig = sg[tid], fg = sg[32 + tid], gg = sg[64 + tid], og = sg[96 + tid];
        float cold = c1b[o + b * 512 + j2];
        float cn = sigm(fg) * cold + sigm(ig) * tanhf(gg);
        float hn = sigm(og) * tanhf(cn);
        c1b[nn + b * 512 + j2] = cn;
        h1b[nn + b * 512 + j2] = hn;
        cat[(long)(b * 64 + t) * 1024 + j2] = f2b(hn);
      }
    }
    gbar(cnt, gen);
  }
}

// ---------------------------------------------------------------------------
extern "C" void kernel_launch(void* const* d_in, const int* in_sizes, int n_in,
                              void* d_out, int out_size, void* d_ws, size_t ws_size,
                              hipStream_t stream) {
  const int*   tgt    = (const int*)d_in[0];
  const float* enc    = (const float*)d_in[1];
  const float* hidden = (const float*)d_in[2];
  const float* cell   = (const float*)d_in[3];
  const float* emb    = (const float*)d_in[4];
  const float* W_a    = (const float*)d_in[5];
  const float* W_ih0  = (const float*)d_in[6];
  const float* W_hh0  = (const float*)d_in[7];
  const float* b_ih0  = (const float*)d_in[8];
  const float* b_hh0  = (const float*)d_in[9];
  const float* W_ih1  = (const float*)d_in[10];
  const float* W_hh1  = (const float*)d_in[11];
  const float* b_ih1  = (const float*)d_in[12];
  const float* b_hh1  = (const float*)d_in[13];
  const float* W_out  = (const float*)d_in[14];
  const float* b_out  = (const float*)d_in[15];
  float* out = (float*)d_out;

  // ---- workspace carve (~74 MB) ----
  char* p = (char*)d_ws;
  auto alloc = [&](size_t bytes) { void* r = p; p += (bytes + 255) & ~(size_t)255; return r; };
  short* woutB = (short*)alloc(32000ULL * 1024 * 2);
  short* catB  = (short*)alloc(2048ULL * 1024 * 2);
  float* encP  = (float*)alloc(2048ULL * 512 * 4);
  float* ctx   = (float*)alloc(32ULL * 512 * 4);
  float* st    = (float*)alloc(8ULL * 16384 * 4);
  unsigned* bar = (unsigned*)alloc(256);
  float* h0b = st, *h1b = st + 2 * 16384, *c0b = st + 4 * 16384, *c1b = st + 6 * 16384;

  // ---- prep ----
  hipLaunchKernelGGL(cvt_bf16_k, dim3(4096), dim3(256), 0, stream, W_out, woutB, 32000L * 1024);
  // encP = enc @ W_a in FP32 (recurrence-critical precision)
  hipLaunchKernelGGL(gemm_f32_k, dim3(8, 32), dim3(256), 0, stream,
                     enc, W_a, encP, 2048, 512, 512, 512);
  hipLaunchKernelGGL(init_states_k, dim3(64), dim3(256), 0, stream, hidden, cell,
                     h0b, h1b, c0b, c1b, bar);

  // ---- recurrence: ONE persistent kernel, 64 steps, 3 hand-rolled gbar/step
  // Grid: 512 if 2 blocks/CU fit (occupancy query), else 256 (unconditionally
  // co-resident on 256 CUs -> barrier can never deadlock).
  {
    int occ = 0;
    hipError_t e = hipOccupancyMaxActiveBlocksPerMultiprocessor(
        &occ, (const void*)decode_loop_k, 256, 0);
    int nblocks = (e == hipSuccess && occ >= 2) ? 512 : 256;
    hipLaunchKernelGGL(decode_loop_k, dim3(nblocks), dim3(256), 0, stream,
                       tgt, emb, enc, encP,
                       W_ih0, W_hh0, b_ih0, b_hh0,
                       W_ih1, W_hh1, b_ih1, b_hh1,
                       ctx, st, catB, bar);
  }

  // ---- final states (after t=63, new state sits in ping-pong slot 0) ----
  hipLaunchKernelGGL(fin_states_k, dim3(64), dim3(256), 0, stream,
                     h0b, h1b, c0b, c1b, out + 65536000L);

  // ---- output projection: [2048x1024] @ [1024x32000] + b_out ----
  hipLaunchKernelGGL(gemm_bf16, dim3(250, 16), dim3(256), 0, stream,
                     catB, woutB, out, b_out,
                     2048, 32000, 1024, 1024, 1024, 32000);
}

// Round 3
// 7905.759 us; speedup vs baseline: 2.1720x; 2.1720x over previous
//
#include <hip/hip_runtime.h>

// ---------------------------------------------------------------------------
// Decoder: B=32, T=64, S=64, V=32000, E=H=512, L=2
// Structure:
//   prep:  cvt W_out->bf16 ; encP = enc @ W_a in FP32 (recurrence-critical!)
//   ONE persistent kernel runs all 64 steps with a HAND-ROLLED grid barrier:
//     stage A: scores = encP . h1 ; softmax ; context      (blocks 0..31)
//     stage B: LSTM cell 0 (gates from [x_t | ctx | h0])   (units, XCD-mapped)
//     stage C: LSTM cell 1 (gates from [h0 | h1]) + cat    (units, XCD-mapped)
//   Barrier (round-2 post-mortem: acquire-polling = per-poll L2 invalidate ->
//   733MB HBM refetch, 85us/barrier): now RELAXED polling + ONE acquire fence
//   on exit, hierarchical arrival (32 padded sub-counters -> master), fan-out
//   release to 32 per-sub generation lines, s_sleep backoff.
//   XCD mapping: unit uu -> (xcd=uu&7, jg=2*xcd+parity, b). Each XCD touches
//   only 2/16 gate-row slices (2.6 MB weights) -> L2-resident, L3-refilled
//   after barrier invalidates instead of HBM.
//   Grid: 512 blocks if occupancy query says 2 blocks/CU fit, else 256.
//   256 blocks x 256 thr are unconditionally co-resident on 256 CUs, so the
//   barrier can never deadlock. Kernel strides work by gridDim.x.
//   epilogue: out = cat @ W_out^T + b_out  (128x128 bf16 MFMA GEMM, M=2048,
//             N=32000, K=1024) ; copy h_f/c_f.
// Precision rule: anything that FEEDS BACK into the recurrence stays fp32.
// bf16 only on the forward-only output projection (error ~0.005 << 0.12).
// ---------------------------------------------------------------------------

typedef __attribute__((ext_vector_type(8))) __bf16 bf16x8;
typedef __attribute__((ext_vector_type(4))) float f32x4;

__device__ __forceinline__ short f2b(float f) {
  unsigned u = __builtin_bit_cast(unsigned, f);
  u += 0x7fffu + ((u >> 16) & 1u);          // round-to-nearest-even
  return (short)(u >> 16);
}

__device__ __forceinline__ float wave_sum(float v) {
  for (int off = 32; off > 0; off >>= 1) v += __shfl_down(v, off);
  return v;                                  // lane 0 holds the sum
}

__device__ __forceinline__ float sigm(float x) { return 1.f / (1.f + expf(-x)); }

// Hierarchical generation grid-barrier (graph-capture-safe, workspace state).
// Layout (uint idx, 128B-padded lines): sub counters bar[32*s] s<32;
// master bar[1024]; per-sub generation bar[1056+32*s] s<32.
// Writers: release fence ONCE before arrival. Spinners: RELAXED polls (no
// per-poll cache invalidate!), ONE acquire fence after exit.
__device__ __forceinline__ void gbar(unsigned* bar, int nb) {
  __syncthreads();                            // drains block's vmcnt (HIP sema)
  if (threadIdx.x == 0) {
    const int sub = blockIdx.x & 31;
    unsigned* genp = bar + 1056 + sub * 32;
    unsigned g = __hip_atomic_load(genp, __ATOMIC_RELAXED, __HIP_MEMORY_SCOPE_AGENT);
    __builtin_amdgcn_fence(__ATOMIC_RELEASE, "agent");
    unsigned a = __hip_atomic_fetch_add(bar + sub * 32, 1u, __ATOMIC_ACQ_REL,
                                        __HIP_MEMORY_SCOPE_AGENT);
    const unsigned subcnt = (unsigned)(nb >> 5);   // nb % 32 == 0 (512 or 256)
    if (a == subcnt - 1u) {                   // last of this sub-group
      __hip_atomic_store(bar + sub * 32, 0u, __ATOMIC_RELAXED, __HIP_MEMORY_SCOPE_AGENT);
      unsigned m = __hip_atomic_fetch_add(bar + 1024, 1u, __ATOMIC_ACQ_REL,
                                          __HIP_MEMORY_SCOPE_AGENT);
      if (m == 31u) {                         // global last: fan-out release
        __hip_atomic_store(bar + 1024, 0u, __ATOMIC_RELAXED, __HIP_MEMORY_SCOPE_AGENT);
        __builtin_amdgcn_fence(__ATOMIC_RELEASE, "agent");
        for (int s = 0; s < 32; s++)
          __hip_atomic_store(bar + 1056 + s * 32, g + 1u, __ATOMIC_RELAXED,
                             __HIP_MEMORY_SCOPE_AGENT);
      }
    }
    while (__hip_atomic_load(genp, __ATOMIC_RELAXED, __HIP_MEMORY_SCOPE_AGENT) == g)
      __builtin_amdgcn_s_sleep(4);
    __builtin_amdgcn_fence(__ATOMIC_ACQUIRE, "agent");
  }
  __syncthreads();
}

// ---------------- converts ----------------
__global__ __launch_bounds__(256) void cvt_bf16_k(const float* __restrict__ in,
                                                  short* __restrict__ out, long n) {
  long stride = (long)gridDim.x * 256 * 4;
  for (long i = ((long)blockIdx.x * 256 + threadIdx.x) * 4; i < n; i += stride) {
    float4 v = *(const float4*)&in[i];
    short4 o; o.x = f2b(v.x); o.y = f2b(v.y); o.z = f2b(v.z); o.w = f2b(v.w);
    *(short4*)&out[i] = o;
  }
}

__global__ __launch_bounds__(256) void init_states_k(const float* __restrict__ hidden,
                                                     const float* __restrict__ cell,
                                                     float* h0, float* h1, float* c0, float* c1,
                                                     unsigned* bar) {
  int i = blockIdx.x * 256 + threadIdx.x;   // grid 64 -> 16384
  h0[i] = hidden[i]; h1[i] = hidden[16384 + i];
  c0[i] = cell[i];   c1[i] = cell[16384 + i];
  if (i < 2176) bar[i] = 0u;                // full barrier state reset per replay
}

__global__ __launch_bounds__(256) void fin_states_k(const float* __restrict__ h0,
                                                    const float* __restrict__ h1,
                                                    const float* __restrict__ c0,
                                                    const float* __restrict__ c1,
                                                    float* __restrict__ out) {
  int i = blockIdx.x * 256 + threadIdx.x;   // grid 64
  out[i] = h0[i]; out[16384 + i] = h1[i];
  out[32768 + i] = c0[i]; out[49152 + i] = c1[i];
}

// ---------------- fp32 GEMM: C[MxN] = A[MxK] @ B[KxN], 64x64 tile, BK=16 ----
__global__ __launch_bounds__(256) void gemm_f32_k(
    const float* __restrict__ A, const float* __restrict__ B,
    float* __restrict__ C, int M, int N, int K, int ldb) {
  __shared__ float As[16][65];
  __shared__ float Bs[16][64];
  int tid = threadIdx.x;
  int tm = blockIdx.y * 64, tn = blockIdx.x * 64;
  int ty = tid >> 4, tx = tid & 15;
  float acc[4][4] = {};
  for (int k0 = 0; k0 < K; k0 += 16) {
    __syncthreads();
    for (int l = 0; l < 4; l++) {
      int idx = l * 256 + tid;            // 0..1023
      int m = idx >> 4, kk = idx & 15;    // A tile: 64m x 16k
      As[kk][m] = A[(long)(tm + m) * K + k0 + kk];
      int kb = idx >> 6, n = idx & 63;    // B tile: 16k x 64n (coalesced)
      Bs[kb][n] = B[(long)(k0 + kb) * ldb + tn + n];
    }
    __syncthreads();
    for (int kk = 0; kk < 16; kk++) {
      float a[4], b[4];
      for (int i = 0; i < 4; i++) a[i] = As[kk][ty * 4 + i];
      for (int j = 0; j < 4; j++) b[j] = Bs[kk][tx * 4 + j];
      for (int i = 0; i < 4; i++)
        for (int j = 0; j < 4; j++) acc[i][j] += a[i] * b[j];
    }
  }
  for (int i = 0; i < 4; i++)
    for (int j = 0; j < 4; j++)
      C[(long)(tm + ty * 4 + i) * N + tn + tx * 4 + j] = acc[i][j];
}

// ---------------- bf16 MFMA GEMM: C[MxN] = A[MxK] * Bt[NxK]^T (+bias) -------
__global__ __launch_bounds__(256) void gemm_bf16(
    const short* __restrict__ A, const short* __restrict__ Bt,
    float* __restrict__ C, const float* __restrict__ bias1,
    int M, int N, int K, int lda, int ldb, int ldc) {
  __shared__ __align__(16) short lsA[8192];
  __shared__ __align__(16) short lsB[8192];
  int tid = threadIdx.x, lane = tid & 63, w = tid >> 6;
  int wm = w >> 1, wn = w & 1;
  int tm = blockIdx.y * 128, tn = blockIdx.x * 128;
  f32x4 acc[4][4] = {};
  int kts = K >> 6;
  for (int kt = 0; kt < kts; kt++) {
    int k0 = kt << 6;
    __syncthreads();
    for (int inst = 0; inst < 4; inst++) {
      int s = w * 256 + inst * 64 + lane;
      int row = s >> 3, cc = s & 7, c = cc ^ (row & 7);
      const short* ga = A + (long)(tm + row) * lda + k0 + c * 8;
      const short* gb = Bt + (long)(tn + row) * ldb + k0 + c * 8;
      __builtin_amdgcn_global_load_lds((const __attribute__((address_space(1))) void*)ga,
                                       (__attribute__((address_space(3))) void*)&lsA[s * 8],
                                       16, 0, 0);
      __builtin_amdgcn_global_load_lds((const __attribute__((address_space(1))) void*)gb,
                                       (__attribute__((address_space(3))) void*)&lsB[s * 8],
                                       16, 0, 0);
    }
    asm volatile("s_waitcnt vmcnt(0)" ::: "memory");
    __syncthreads();
    for (int ks = 0; ks < 2; ks++) {
      bf16x8 af[4], bfr[4];
      for (int mt = 0; mt < 4; mt++) {
        int row = wm * 64 + mt * 16 + (lane & 15);
        int c = ks * 4 + (lane >> 4);
        int slot = row * 8 + (c ^ (row & 7));
        af[mt] = *(const bf16x8*)&lsA[slot * 8];
      }
      for (int nt = 0; nt < 4; nt++) {
        int row = wn * 64 + nt * 16 + (lane & 15);
        int c = ks * 4 + (lane >> 4);
        int slot = row * 8 + (c ^ (row & 7));
        bfr[nt] = *(const bf16x8*)&lsB[slot * 8];
      }
      for (int mt = 0; mt < 4; mt++)
        for (int nt = 0; nt < 4; nt++)
          acc[mt][nt] = __builtin_amdgcn_mfma_f32_16x16x32_bf16(af[mt], bfr[nt], acc[mt][nt], 0, 0, 0);
    }
  }
  for (int nt = 0; nt < 4; nt++) {
    int ccol = tn + wn * 64 + nt * 16 + (lane & 15);
    float bsum = bias1 ? bias1[ccol] : 0.f;
    for (int mt = 0; mt < 4; mt++) {
      int r0 = tm + wm * 64 + mt * 16 + ((lane >> 4) << 2);
      f32x4 v = acc[mt][nt];
      for (int r = 0; r < 4; r++)
        C[(long)(r0 + r) * ldc + ccol] = v[r] + bsum;
    }
  }
}

// ---------------- persistent recurrence: all 64 steps, 3 gbar/step ----------
// Grid-size-agnostic: stages B/C stride 512 units by gridDim.x via uu, with
// XCD-aware decode: xcd=uu&7, jg=2*xcd+(parity), b — under round-robin block
// placement each XCD touches only 2/16 weight row-slices (2.6MB, L2-fits).
__global__ __launch_bounds__(256, 2) void decode_loop_k(
    const int* __restrict__ tgt, const float* __restrict__ emb,
    const float* __restrict__ enc, const float* __restrict__ encP,
    const float* __restrict__ Wih0, const float* __restrict__ Whh0,
    const float* __restrict__ bih0, const float* __restrict__ bhh0,
    const float* __restrict__ Wih1, const float* __restrict__ Whh1,
    const float* __restrict__ bih1, const float* __restrict__ bhh1,
    float* __restrict__ ctx, float* __restrict__ st, short* __restrict__ cat,
    unsigned* __restrict__ bar) {
  __shared__ __align__(16) float sinp[1536];   // A: sh1[512] ; B: [x|ctx|h0] ; C: [h0|h1]
  __shared__ float sg[128];                    // A: sattn[64] ; B/C: gate partials
  const int g = blockIdx.x, nb = gridDim.x;
  const int tid = threadIdx.x, lane = tid & 63, w = tid >> 6;
  float* h0b = st;
  float* h1b = st + 2 * 16384;
  float* c0b = st + 4 * 16384;
  float* c1b = st + 6 * 16384;

#pragma unroll 1
  for (int t = 0; t < 64; t++) {
    const int o = (t & 1) * 16384, nn = ((t & 1) ^ 1) * 16384;

    // ---- stage A: attention (blocks 0..31, one per batch) ----
    if (g < 32) {
      const int b = g;
      const float* h1o = h1b + o;
      sinp[tid] = h1o[b * 512 + tid];
      sinp[256 + tid] = h1o[b * 512 + 256 + tid];
      __syncthreads();
      for (int i = 0; i < 16; i++) {
        int s = w * 16 + i;
        const float* ep = encP + (long)(b * 64 + s) * 512;
        float acc = 0.f;
        for (int kk = 0; kk < 2; kk++) {
          float4 ev = *(const float4*)&ep[(kk * 64 + lane) * 4];
          float4 hv = *(const float4*)&sinp[(kk * 64 + lane) * 4];
          acc += ev.x * hv.x + ev.y * hv.y + ev.z * hv.z + ev.w * hv.w;
        }
        acc = wave_sum(acc);
        if (lane == 0) sg[s] = acc;
      }
      __syncthreads();
      if (w == 0) {
        float v = sg[lane];
        float m = v;
        for (int off = 32; off > 0; off >>= 1) m = fmaxf(m, __shfl_xor(m, off));
        float e = expf(v - m);
        float ssum = e;
        for (int off = 32; off > 0; off >>= 1) ssum += __shfl_xor(ssum, off);
        sg[lane] = e / ssum;
      }
      __syncthreads();
      for (int h = tid; h < 512; h += 256) {
        float c = 0.f;
        for (int s = 0; s < 64; s++) c += sg[s] * enc[(long)(b * 64 + s) * 512 + h];
        ctx[b * 512 + h] = c;
        cat[(long)(b * 64 + t) * 1024 + 512 + h] = f2b(c);
      }
    }
    gbar(bar, nb);

    // ---- stage B: LSTM layer 0 (512 units, XCD-aware decode) ----
    for (int uu = g; uu < 512; uu += nb) {
      const int x = uu & 7, k = uu >> 3;
      const int jg = (x << 1) | (k & 1), b = k >> 1;
      __syncthreads();                         // prev unit's sinp/sg reads done
      int idx = tgt[b * 64 + t];
      const float* xrow = emb + (long)idx * 512;
      for (int kk2 = tid; kk2 < 512; kk2 += 256) {
        sinp[kk2] = (idx == 0) ? 0.f : xrow[kk2];  // padding_idx=0
        sinp[512 + kk2] = ctx[b * 512 + kk2];
        sinp[1024 + kk2] = h0b[o + b * 512 + kk2];
      }
      __syncthreads();
      for (int i = 0; i < 32; i++) {
        int j = w * 512 + jg * 32 + i;         // gate row (w = gate quadrant)
        const float4* w1 = (const float4*)(Wih0 + (long)j * 1024);
        const float4* w2 = (const float4*)(Whh0 + (long)j * 512);
        float acc = 0.f;
        for (int kk = 0; kk < 4; kk++) {
          float4 wv = w1[kk * 64 + lane];
          float4 iv = *(const float4*)&sinp[(kk * 64 + lane) * 4];
          acc += wv.x * iv.x + wv.y * iv.y + wv.z * iv.z + wv.w * iv.w;
        }
        for (int kk = 0; kk < 2; kk++) {
          float4 wv = w2[kk * 64 + lane];
          float4 iv = *(const float4*)&sinp[1024 + (kk * 64 + lane) * 4];
          acc += wv.x * iv.x + wv.y * iv.y + wv.z * iv.z + wv.w * iv.w;
        }
        acc = wave_sum(acc);
        if (lane == 0) sg[w * 32 + i] = acc + bih0[j] + bhh0[j];
      }
      __syncthreads();
      if (tid < 32) {
        int j2 = jg * 32 + tid;
        float ig = sg[tid], fg = sg[32 + tid], gg = sg[64 + tid], og = sg[96 + tid];
        float cold = c0b[o + b * 512 + j2];
        float cn = sigm(fg) * cold + sigm(ig) * tanhf(gg);
        float hn = sigm(og) * tanhf(cn);
        c0b[nn + b * 512 + j2] = cn;
        h0b[nn + b * 512 + j2] = hn;
      }
    }
    gbar(bar, nb);

    // ---- stage C: LSTM layer 1 + cat write ----
    for (int uu = g; uu < 512; uu += nb) {
      const int x = uu & 7, k = uu >> 3;
      const int jg = (x << 1) | (k & 1), b = k >> 1;
      __syncthreads();
      for (int kk2 = tid; kk2 < 512; kk2 += 256) {
        sinp[kk2] = h0b[nn + b * 512 + kk2];
        sinp[512 + kk2] = h1b[o + b * 512 + kk2];
      }
      __syncthreads();
      for (int i = 0; i < 32; i++) {
        int j = w * 512 + jg * 32 + i;
        const float4* w1 = (const float4*)(Wih1 + (long)j * 512);
        const float4* w2 = (const float4*)(Whh1 + (long)j * 512);
        float acc = 0.f;
        for (int kk = 0; kk < 2; kk++) {
          float4 wv = w1[kk * 64 + lane];
          float4 iv = *(const float4*)&sinp[(kk * 64 + lane) * 4];
          acc += wv.x * iv.x + wv.y * iv.y + wv.z * iv.z + wv.w * iv.w;
        }
        for (int kk = 0; kk < 2; kk++) {
          float4 wv = w2[kk * 64 + lane];
          float4 iv = *(const float4*)&sinp[512 + (kk * 64 + lane) * 4];
          acc += wv.x * iv.x + wv.y * iv.y + wv.z * iv.z + wv.w * iv.w;
        }
        acc = wave_sum(acc);
        if (lane == 0) sg[w * 32 + i] = acc + bih1[j] + bhh1[j];
      }
      __syncthreads();
      if (tid < 32) {
        int j2 = jg * 32 + tid;
        float ig = sg[tid], fg = sg[32 + tid], gg = sg[64 + tid], og = sg[96 + tid];
        float cold = c1b[o + b * 512 + j2];
        float cn = sigm(fg) * cold + sigm(ig) * tanhf(gg);
        float hn = sigm(og) * tanhf(cn);
        c1b[nn + b * 512 + j2] = cn;
        h1b[nn + b * 512 + j2] = hn;
        cat[(long)(b * 64 + t) * 1024 + j2] = f2b(hn);
      }
    }
    gbar(bar, nb);
  }
}

// ---------------------------------------------------------------------------
extern "C" void kernel_launch(void* const* d_in, const int* in_sizes, int n_in,
                              void* d_out, int out_size, void* d_ws, size_t ws_size,
                              hipStream_t stream) {
  const int*   tgt    = (const int*)d_in[0];
  const float* enc    = (const float*)d_in[1];
  const float* hidden = (const float*)d_in[2];
  const float* cell   = (const float*)d_in[3];
  const float* emb    = (const float*)d_in[4];
  const float* W_a    = (const float*)d_in[5];
  const float* W_ih0  = (const float*)d_in[6];
  const float* W_hh0  = (const float*)d_in[7];
  const float* b_ih0  = (const float*)d_in[8];
  const float* b_hh0  = (const float*)d_in[9];
  const float* W_ih1  = (const float*)d_in[10];
  const float* W_hh1  = (const float*)d_in[11];
  const float* b_ih1  = (const float*)d_in[12];
  const float* b_hh1  = (const float*)d_in[13];
  const float* W_out  = (const float*)d_in[14];
  const float* b_out  = (const float*)d_in[15];
  float* out = (float*)d_out;

  // ---- workspace carve (~74 MB) ----
  char* p = (char*)d_ws;
  auto alloc = [&](size_t bytes) { void* r = p; p += (bytes + 255) & ~(size_t)255; return r; };
  short* woutB = (short*)alloc(32000ULL * 1024 * 2);
  short* catB  = (short*)alloc(2048ULL * 1024 * 2);
  float* encP  = (float*)alloc(2048ULL * 512 * 4);
  float* ctx   = (float*)alloc(32ULL * 512 * 4);
  float* st    = (float*)alloc(8ULL * 16384 * 4);
  unsigned* bar = (unsigned*)alloc(16384);
  float* h0b = st, *h1b = st + 2 * 16384, *c0b = st + 4 * 16384, *c1b = st + 6 * 16384;

  // ---- prep ----
  hipLaunchKernelGGL(cvt_bf16_k, dim3(4096), dim3(256), 0, stream, W_out, woutB, 32000L * 1024);
  // encP = enc @ W_a in FP32 (recurrence-critical precision)
  hipLaunchKernelGGL(gemm_f32_k, dim3(8, 32), dim3(256), 0, stream,
                     enc, W_a, encP, 2048, 512, 512, 512);
  hipLaunchKernelGGL(init_states_k, dim3(64), dim3(256), 0, stream, hidden, cell,
                     h0b, h1b, c0b, c1b, bar);

  // ---- recurrence: ONE persistent kernel, 64 steps, 3 hand-rolled gbar/step
  // Grid: 512 if 2 blocks/CU fit (occupancy query), else 256 (unconditionally
  // co-resident on 256 CUs -> barrier can never deadlock).
  {
    int occ = 0;
    hipError_t e = hipOccupancyMaxActiveBlocksPerMultiprocessor(
        &occ, (const void*)decode_loop_k, 256, 0);
    int nblocks = (e == hipSuccess && occ >= 2) ? 512 : 256;
    hipLaunchKernelGGL(decode_loop_k, dim3(nblocks), dim3(256), 0, stream,
                       tgt, emb, enc, encP,
                       W_ih0, W_hh0, b_ih0, b_hh0,
                       W_ih1, W_hh1, b_ih1, b_hh1,
                       ctx, st, catB, bar);
  }

  // ---- final states (after t=63, new state sits in ping-pong slot 0) ----
  hipLaunchKernelGGL(fin_states_k, dim3(64), dim3(256), 0, stream,
                     h0b, h1b, c0b, c1b, out + 65536000L);

  // ---- output projection: [2048x1024] @ [1024x32000] + b_out ----
  hipLaunchKernelGGL(gemm_bf16, dim3(250, 16), dim3(256), 0, stream,
                     catB, woutB, out, b_out,
                     2048, 32000, 1024, 1024, 1024, 32000);
}

// Round 4
// 4937.223 us; speedup vs baseline: 3.4780x; 1.6013x over previous
//
#include <hip/hip_runtime.h>

// ---------------------------------------------------------------------------
// Decoder: B=32, T=64, S=64, V=32000, E=H=512, L=2
// Structure:
//   prep:  cvt W_out->bf16 ; encP = enc @ W_a in FP32 (recurrence-critical!)
//   ONE persistent kernel runs all 64 steps with a HAND-ROLLED grid barrier:
//     stage A: scores = encP . h1 ; softmax ; context      (blocks 0..31)
//     stage B: LSTM cell 0, BATCH-PAIRED (unit = jh row-slice x batch-pair)
//     stage C: LSTM cell 1, BATCH-PAIRED, + cat write
//   ROUND-4 KEY FIX (round-3 post-mortem: FETCH=725MB unchanged, 11.3MB/step
//   of weight refetch WAS the critical path at 111GB/s): the barrier's
//   ACQ_REL arrival + acquire fence lowered to buffer_inv on EVERY block at
//   EVERY barrier -> L2 never kept the 20MB of weights. Now:
//     - ALL barrier atomics RELAXED (no acquire/release => no buffer_inv /
//       buffer_wbl2 anywhere in the loop). Ordering via s_waitcnt vmcnt(0)
//       (__syncthreads already drains vmcnt per-wave before arrival).
//     - Cross-block state (h*,c*,ctx ~100KB) uses device-coherent BYPASS
//       accesses (__hip_atomic_load/store RELAXED AGENT, 8B/4B): they execute
//       at the coherence point (L3), so no invalidate is ever needed.
//     - Weights/emb/enc/encP stay plain loads -> permanently L1/L2-hot.
//     - Batch-pairing: each weight float4 feeds TWO batches' dots (halves L2
//       weight traffic). XCD mapping keeps each XCD's slice ~2.5MB L2-fit.
//   Grid: 512 blocks if occupancy query says 2 blocks/CU fit, else 256
//   (256 blocks x 256 thr are unconditionally co-resident -> no deadlock).
//   epilogue: out = cat @ W_out^T + b_out  (128x128 bf16 MFMA GEMM).
// Precision rule: anything that FEEDS BACK into the recurrence stays fp32.
// bf16 only on the forward-only output projection (error ~0.005 << 0.12).
// ---------------------------------------------------------------------------

typedef __attribute__((ext_vector_type(8))) __bf16 bf16x8;
typedef __attribute__((ext_vector_type(4))) float f32x4;

__device__ __forceinline__ short f2b(float f) {
  unsigned u = __builtin_bit_cast(unsigned, f);
  u += 0x7fffu + ((u >> 16) & 1u);          // round-to-nearest-even
  return (short)(u >> 16);
}

__device__ __forceinline__ float wave_sum(float v) {
  for (int off = 32; off > 0; off >>= 1) v += __shfl_down(v, off);
  return v;                                  // lane 0 holds the sum
}

__device__ __forceinline__ float sigm(float x) { return 1.f / (1.f + expf(-x)); }

// Device-coherent bypass accessors for cross-block state. RELAXED+AGENT
// atomics execute at the device coherence point (bypass stale L1/L2) with
// NO cache-maintenance ops emitted. 8B and 4B granules.
__device__ __forceinline__ float2 ld_cg2(const float* p) {
  unsigned long long u = __hip_atomic_load((const unsigned long long*)p,
      __ATOMIC_RELAXED, __HIP_MEMORY_SCOPE_AGENT);
  return __builtin_bit_cast(float2, u);
}
__device__ __forceinline__ void st_cg2(float* p, float2 v) {
  __hip_atomic_store((unsigned long long*)p,
      __builtin_bit_cast(unsigned long long, v),
      __ATOMIC_RELAXED, __HIP_MEMORY_SCOPE_AGENT);
}
__device__ __forceinline__ float ld_cg1(const float* p) {
  return __hip_atomic_load(p, __ATOMIC_RELAXED, __HIP_MEMORY_SCOPE_AGENT);
}
__device__ __forceinline__ void st_cg1(float* p, float v) {
  __hip_atomic_store(p, v, __ATOMIC_RELAXED, __HIP_MEMORY_SCOPE_AGENT);
}

// Hierarchical generation grid-barrier, ALL-RELAXED (no buffer_inv!).
// Layout (uint idx, 128B lines): sub counters bar[32*s] s<32; master
// bar[1024]; per-sub generation bar[1056+32*s] s<32.
// Visibility: state producers use write-through st_cg*; __syncthreads at
// entry drains each wave's vmcnt, so stores are at the coherence point
// before the (relaxed, device-atomic) arrival increments. Consumers re-read
// state with ld_cg* -> no invalidate needed anywhere.
__device__ __forceinline__ void gbar(unsigned* bar, int nb) {
  __syncthreads();                            // per-wave vmcnt(0) + s_barrier
  if (threadIdx.x == 0) {
    const int sub = blockIdx.x & 31;
    unsigned* genp = bar + 1056 + sub * 32;
    unsigned g = __hip_atomic_load(genp, __ATOMIC_RELAXED, __HIP_MEMORY_SCOPE_AGENT);
    asm volatile("s_waitcnt vmcnt(0)" ::: "memory");
    unsigned a = __hip_atomic_fetch_add(bar + sub * 32, 1u, __ATOMIC_RELAXED,
                                        __HIP_MEMORY_SCOPE_AGENT);
    const unsigned subcnt = (unsigned)(nb >> 5);   // nb % 32 == 0 (512 or 256)
    if (a == subcnt - 1u) {                   // last of this sub-group
      __hip_atomic_store(bar + sub * 32, 0u, __ATOMIC_RELAXED, __HIP_MEMORY_SCOPE_AGENT);
      asm volatile("s_waitcnt vmcnt(0)" ::: "memory");  // reset committed first
      unsigned m = __hip_atomic_fetch_add(bar + 1024, 1u, __ATOMIC_RELAXED,
                                          __HIP_MEMORY_SCOPE_AGENT);
      if (m == 31u) {                         // global last: fan-out release
        __hip_atomic_store(bar + 1024, 0u, __ATOMIC_RELAXED, __HIP_MEMORY_SCOPE_AGENT);
        asm volatile("s_waitcnt vmcnt(0)" ::: "memory");
        for (int s = 0; s < 32; s++)
          __hip_atomic_store(bar + 1056 + s * 32, g + 1u, __ATOMIC_RELAXED,
                             __HIP_MEMORY_SCOPE_AGENT);
      }
    }
    while (__hip_atomic_load(genp, __ATOMIC_RELAXED, __HIP_MEMORY_SCOPE_AGENT) == g)
      __builtin_amdgcn_s_sleep(4);
  }
  __syncthreads();
}

// ---------------- converts ----------------
__global__ __launch_bounds__(256) void cvt_bf16_k(const float* __restrict__ in,
                                                  short* __restrict__ out, long n) {
  long stride = (long)gridDim.x * 256 * 4;
  for (long i = ((long)blockIdx.x * 256 + threadIdx.x) * 4; i < n; i += stride) {
    float4 v = *(const float4*)&in[i];
    short4 o; o.x = f2b(v.x); o.y = f2b(v.y); o.z = f2b(v.z); o.w = f2b(v.w);
    *(short4*)&out[i] = o;
  }
}

__global__ __launch_bounds__(256) void init_states_k(const float* __restrict__ hidden,
                                                     const float* __restrict__ cell,
                                                     float* h0, float* h1, float* c0, float* c1,
                                                     unsigned* bar) {
  int i = blockIdx.x * 256 + threadIdx.x;   // grid 64 -> 16384
  h0[i] = hidden[i]; h1[i] = hidden[16384 + i];
  c0[i] = cell[i];   c1[i] = cell[16384 + i];
  if (i < 2176) bar[i] = 0u;                // full barrier state reset per replay
}

__global__ __launch_bounds__(256) void fin_states_k(const float* __restrict__ h0,
                                                    const float* __restrict__ h1,
                                                    const float* __restrict__ c0,
                                                    const float* __restrict__ c1,
                                                    float* __restrict__ out) {
  int i = blockIdx.x * 256 + threadIdx.x;   // grid 64
  out[i] = h0[i]; out[16384 + i] = h1[i];
  out[32768 + i] = c0[i]; out[49152 + i] = c1[i];
}

// ---------------- fp32 GEMM: C[MxN] = A[MxK] @ B[KxN], 64x64 tile, BK=16 ----
__global__ __launch_bounds__(256) void gemm_f32_k(
    const float* __restrict__ A, const float* __restrict__ B,
    float* __restrict__ C, int M, int N, int K, int ldb) {
  __shared__ float As[16][65];
  __shared__ float Bs[16][64];
  int tid = threadIdx.x;
  int tm = blockIdx.y * 64, tn = blockIdx.x * 64;
  int ty = tid >> 4, tx = tid & 15;
  float acc[4][4] = {};
  for (int k0 = 0; k0 < K; k0 += 16) {
    __syncthreads();
    for (int l = 0; l < 4; l++) {
      int idx = l * 256 + tid;            // 0..1023
      int m = idx >> 4, kk = idx & 15;    // A tile: 64m x 16k
      As[kk][m] = A[(long)(tm + m) * K + k0 + kk];
      int kb = idx >> 6, n = idx & 63;    // B tile: 16k x 64n (coalesced)
      Bs[kb][n] = B[(long)(k0 + kb) * ldb + tn + n];
    }
    __syncthreads();
    for (int kk = 0; kk < 16; kk++) {
      float a[4], b[4];
      for (int i = 0; i < 4; i++) a[i] = As[kk][ty * 4 + i];
      for (int j = 0; j < 4; j++) b[j] = Bs[kk][tx * 4 + j];
      for (int i = 0; i < 4; i++)
        for (int j = 0; j < 4; j++) acc[i][j] += a[i] * b[j];
    }
  }
  for (int i = 0; i < 4; i++)
    for (int j = 0; j < 4; j++)
      C[(long)(tm + ty * 4 + i) * N + tn + tx * 4 + j] = acc[i][j];
}

// ---------------- bf16 MFMA GEMM: C[MxN] = A[MxK] * Bt[NxK]^T (+bias) -------
__global__ __launch_bounds__(256) void gemm_bf16(
    const short* __restrict__ A, const short* __restrict__ Bt,
    float* __restrict__ C, const float* __restrict__ bias1,
    int M, int N, int K, int lda, int ldb, int ldc) {
  __shared__ __align__(16) short lsA[8192];
  __shared__ __align__(16) short lsB[8192];
  int tid = threadIdx.x, lane = tid & 63, w = tid >> 6;
  int wm = w >> 1, wn = w & 1;
  int tm = blockIdx.y * 128, tn = blockIdx.x * 128;
  f32x4 acc[4][4] = {};
  int kts = K >> 6;
  for (int kt = 0; kt < kts; kt++) {
    int k0 = kt << 6;
    __syncthreads();
    for (int inst = 0; inst < 4; inst++) {
      int s = w * 256 + inst * 64 + lane;
      int row = s >> 3, cc = s & 7, c = cc ^ (row & 7);
      const short* ga = A + (long)(tm + row) * lda + k0 + c * 8;
      const short* gb = Bt + (long)(tn + row) * ldb + k0 + c * 8;
      __builtin_amdgcn_global_load_lds((const __attribute__((address_space(1))) void*)ga,
                                       (__attribute__((address_space(3))) void*)&lsA[s * 8],
                                       16, 0, 0);
      __builtin_amdgcn_global_load_lds((const __attribute__((address_space(1))) void*)gb,
                                       (__attribute__((address_space(3))) void*)&lsB[s * 8],
                                       16, 0, 0);
    }
    asm volatile("s_waitcnt vmcnt(0)" ::: "memory");
    __syncthreads();
    for (int ks = 0; ks < 2; ks++) {
      bf16x8 af[4], bfr[4];
      for (int mt = 0; mt < 4; mt++) {
        int row = wm * 64 + mt * 16 + (lane & 15);
        int c = ks * 4 + (lane >> 4);
        int slot = row * 8 + (c ^ (row & 7));
        af[mt] = *(const bf16x8*)&lsA[slot * 8];
      }
      for (int nt = 0; nt < 4; nt++) {
        int row = wn * 64 + nt * 16 + (lane & 15);
        int c = ks * 4 + (lane >> 4);
        int slot = row * 8 + (c ^ (row & 7));
        bfr[nt] = *(const bf16x8*)&lsB[slot * 8];
      }
      for (int mt = 0; mt < 4; mt++)
        for (int nt = 0; nt < 4; nt++)
          acc[mt][nt] = __builtin_amdgcn_mfma_f32_16x16x32_bf16(af[mt], bfr[nt], acc[mt][nt], 0, 0, 0);
    }
  }
  for (int nt = 0; nt < 4; nt++) {
    int ccol = tn + wn * 64 + nt * 16 + (lane & 15);
    float bsum = bias1 ? bias1[ccol] : 0.f;
    for (int mt = 0; mt < 4; mt++) {
      int r0 = tm + wm * 64 + mt * 16 + ((lane >> 4) << 2);
      f32x4 v = acc[mt][nt];
      for (int r = 0; r < 4; r++)
        C[(long)(r0 + r) * ldc + ccol] = v[r] + bsum;
    }
  }
}

// ---------------- persistent recurrence: all 64 steps, 3 gbar/step ----------
// Stage B/C unit = (jh 0..31 row-slice of 16 rows/quadrant, bp 0..15 batch
// pair). Each weight float4 is dotted with TWO batches' inputs (halves L2
// weight traffic). XCD decode: x=uu&7 -> jh in {4x..4x+3}: each XCD's slice
// is ~2.5MB -> L2-resident (weights are plain loads, never invalidated).
__global__ __launch_bounds__(256, 2) void decode_loop_k(
    const int* __restrict__ tgt, const float* __restrict__ emb,
    const float* __restrict__ enc, const float* __restrict__ encP,
    const float* __restrict__ Wih0, const float* __restrict__ Whh0,
    const float* __restrict__ bih0, const float* __restrict__ bhh0,
    const float* __restrict__ Wih1, const float* __restrict__ Whh1,
    const float* __restrict__ bih1, const float* __restrict__ bhh1,
    float* __restrict__ ctx, float* __restrict__ st, short* __restrict__ cat,
    unsigned* __restrict__ bar) {
  __shared__ __align__(16) float sinp[3072];   // B: 2x[x|ctx|h0] ; C: 2x[h0|h1]
  __shared__ float sg[128];                    // A: sattn[64] ; B/C: 2x64 gates
  const int g = blockIdx.x, nb = gridDim.x;
  const int tid = threadIdx.x, lane = tid & 63, w = tid >> 6;
  float* h0b = st;
  float* h1b = st + 2 * 16384;
  float* c0b = st + 4 * 16384;
  float* c1b = st + 6 * 16384;

#pragma unroll 1
  for (int t = 0; t < 64; t++) {
    const int o = (t & 1) * 16384, nn = ((t & 1) ^ 1) * 16384;

    // ---- stage A: attention (blocks 0..31, one per batch) ----
    if (g < 32) {
      const int b = g;
      float2 hv = ld_cg2(h1b + o + b * 512 + tid * 2);   // coherent h1 read
      *(float2*)&sinp[tid * 2] = hv;
      __syncthreads();
      for (int i = 0; i < 16; i++) {
        int s = w * 16 + i;
        const float* ep = encP + (long)(b * 64 + s) * 512;
        float acc = 0.f;
        for (int kk = 0; kk < 2; kk++) {
          float4 ev = *(const float4*)&ep[(kk * 64 + lane) * 4];
          float4 iv = *(const float4*)&sinp[(kk * 64 + lane) * 4];
          acc += ev.x * iv.x + ev.y * iv.y + ev.z * iv.z + ev.w * iv.w;
        }
        acc = wave_sum(acc);
        if (lane == 0) sg[s] = acc;
      }
      __syncthreads();
      if (w == 0) {
        float v = sg[lane];
        float m = v;
        for (int off = 32; off > 0; off >>= 1) m = fmaxf(m, __shfl_xor(m, off));
        float e = expf(v - m);
        float ssum = e;
        for (int off = 32; off > 0; off >>= 1) ssum += __shfl_xor(ssum, off);
        sg[lane] = e / ssum;
      }
      __syncthreads();
      for (int h = tid; h < 512; h += 256) {
        float c = 0.f;
        for (int s = 0; s < 64; s++) c += sg[s] * enc[(long)(b * 64 + s) * 512 + h];
        st_cg1(&ctx[b * 512 + h], c);                    // coherent publish
        cat[(long)(b * 64 + t) * 1024 + 512 + h] = f2b(c);
      }
    }
    gbar(bar, nb);

    // ---- stage B: LSTM layer 0 (512 units = 32 jh x 16 bp, 2 batches) ----
    for (int uu = g; uu < 512; uu += nb) {
      const int x = uu & 7, r = uu >> 3;
      const int jh = x * 4 + (r & 3);          // row-slice 0..31 (XCD-grouped)
      const int bp = r >> 2;                   // batch pair 0..15
      const int b0 = bp * 2, b1 = b0 + 1;
      __syncthreads();                         // prev unit's LDS reads done
      int idxA = tgt[b0 * 64 + t], idxB = tgt[b1 * 64 + t];
      const float* xrowA = emb + (long)idxA * 512;
      const float* xrowB = emb + (long)idxB * 512;
      {
        int k = tid * 2;
        float2 z = {0.f, 0.f};
        *(float2*)&sinp[k] = (idxA == 0) ? z : *(const float2*)&xrowA[k];
        *(float2*)&sinp[512 + k] = ld_cg2(&ctx[b0 * 512 + k]);
        *(float2*)&sinp[1024 + k] = ld_cg2(&h0b[o + b0 * 512 + k]);
        *(float2*)&sinp[1536 + k] = (idxB == 0) ? z : *(const float2*)&xrowB[k];
        *(float2*)&sinp[2048 + k] = ld_cg2(&ctx[b1 * 512 + k]);
        *(float2*)&sinp[2560 + k] = ld_cg2(&h0b[o + b1 * 512 + k]);
      }
      __syncthreads();
      for (int i = 0; i < 16; i++) {
        int j = w * 512 + jh * 16 + i;         // gate row (w = gate quadrant)
        const float4* w1 = (const float4*)(Wih0 + (long)j * 1024);
        const float4* w2 = (const float4*)(Whh0 + (long)j * 512);
        float a0 = 0.f, a1 = 0.f;
        for (int kk = 0; kk < 4; kk++) {
          float4 wv = w1[kk * 64 + lane];
          float4 i0 = *(const float4*)&sinp[(kk * 64 + lane) * 4];
          float4 i1 = *(const float4*)&sinp[1536 + (kk * 64 + lane) * 4];
          a0 += wv.x * i0.x + wv.y * i0.y + wv.z * i0.z + wv.w * i0.w;
          a1 += wv.x * i1.x + wv.y * i1.y + wv.z * i1.z + wv.w * i1.w;
        }
        for (int kk = 0; kk < 2; kk++) {
          float4 wv = w2[kk * 64 + lane];
          float4 i0 = *(const float4*)&sinp[1024 + (kk * 64 + lane) * 4];
          float4 i1 = *(const float4*)&sinp[2560 + (kk * 64 + lane) * 4];
          a0 += wv.x * i0.x + wv.y * i0.y + wv.z * i0.z + wv.w * i0.w;
          a1 += wv.x * i1.x + wv.y * i1.y + wv.z * i1.z + wv.w * i1.w;
        }
        a0 = wave_sum(a0); a1 = wave_sum(a1);
        if (lane == 0) {
          float bb = bih0[j] + bhh0[j];
          sg[w * 16 + i] = a0 + bb;            // batch0 gates: sg[0..63]
          sg[64 + w * 16 + i] = a1 + bb;       // batch1 gates: sg[64..127]
        }
      }
      __syncthreads();
      if (tid < 32) {
        int bsel = tid >> 4, rr = tid & 15;
        int b = b0 + bsel, j2 = jh * 16 + rr;
        const float* s = sg + bsel * 64;
        float ig = s[rr], fg = s[16 + rr], gg = s[32 + rr], og = s[48 + rr];
        float cold = ld_cg1(&c0b[o + b * 512 + j2]);
        float cn = sigm(fg) * cold + sigm(ig) * tanhf(gg);
        float hn = sigm(og) * tanhf(cn);
        st_cg1(&c0b[nn + b * 512 + j2], cn);
        st_cg1(&h0b[nn + b * 512 + j2], hn);
      }
    }
    gbar(bar, nb);

    // ---- stage C: LSTM layer 1 + cat write (same unit decomposition) ----
    for (int uu = g; uu < 512; uu += nb) {
      const int x = uu & 7, r = uu >> 3;
      const int jh = x * 4 + (r & 3);
      const int bp = r >> 2;
      const int b0 = bp * 2, b1 = b0 + 1;
      __syncthreads();
      {
        int k = tid * 2;
        *(float2*)&sinp[k]        = ld_cg2(&h0b[nn + b0 * 512 + k]);
        *(float2*)&sinp[512 + k]  = ld_cg2(&h1b[o + b0 * 512 + k]);
        *(float2*)&sinp[1024 + k] = ld_cg2(&h0b[nn + b1 * 512 + k]);
        *(float2*)&sinp[1536 + k] = ld_cg2(&h1b[o + b1 * 512 + k]);
      }
      __syncthreads();
      for (int i = 0; i < 16; i++) {
        int j = w * 512 + jh * 16 + i;
        const float4* w1 = (const float4*)(Wih1 + (long)j * 512);
        const float4* w2 = (const float4*)(Whh1 + (long)j * 512);
        float a0 = 0.f, a1 = 0.f;
        for (int kk = 0; kk < 2; kk++) {
          float4 wv = w1[kk * 64 + lane];
          float4 i0 = *(const float4*)&sinp[(kk * 64 + lane) * 4];
          float4 i1 = *(const float4*)&sinp[1024 + (kk * 64 + lane) * 4];
          a0 += wv.x * i0.x + wv.y * i0.y + wv.z * i0.z + wv.w * i0.w;
          a1 += wv.x * i1.x + wv.y * i1.y + wv.z * i1.z + wv.w * i1.w;
        }
        for (int kk = 0; kk < 2; kk++) {
          float4 wv = w2[kk * 64 + lane];
          float4 i0 = *(const float4*)&sinp[512 + (kk * 64 + lane) * 4];
          float4 i1 = *(const float4*)&sinp[1536 + (kk * 64 + lane) * 4];
          a0 += wv.x * i0.x + wv.y * i0.y + wv.z * i0.z + wv.w * i0.w;
          a1 += wv.x * i1.x + wv.y * i1.y + wv.z * i1.z + wv.w * i1.w;
        }
        a0 = wave_sum(a0); a1 = wave_sum(a1);
        if (lane == 0) {
          float bb = bih1[j] + bhh1[j];
          sg[w * 16 + i] = a0 + bb;
          sg[64 + w * 16 + i] = a1 + bb;
        }
      }
      __syncthreads();
      if (tid < 32) {
        int bsel = tid >> 4, rr = tid & 15;
        int b = b0 + bsel, j2 = jh * 16 + rr;
        const float* s = sg + bsel * 64;
        float ig = s[rr], fg = s[16 + rr], gg = s[32 + rr], og = s[48 + rr];
        float cold = ld_cg1(&c1b[o + b * 512 + j2]);
        float cn = sigm(fg) * cold + sigm(ig) * tanhf(gg);
        float hn = sigm(og) * tanhf(cn);
        st_cg1(&c1b[nn + b * 512 + j2], cn);
        st_cg1(&h1b[nn + b * 512 + j2], hn);
        cat[(long)(b * 64 + t) * 1024 + j2] = f2b(hn);
      }
    }
    gbar(bar, nb);
  }
}

// ---------------------------------------------------------------------------
extern "C" void kernel_launch(void* const* d_in, const int* in_sizes, int n_in,
                              void* d_out, int out_size, void* d_ws, size_t ws_size,
                              hipStream_t stream) {
  const int*   tgt    = (const int*)d_in[0];
  const float* enc    = (const float*)d_in[1];
  const float* hidden = (const float*)d_in[2];
  const float* cell   = (const float*)d_in[3];
  const float* emb    = (const float*)d_in[4];
  const float* W_a    = (const float*)d_in[5];
  const float* W_ih0  = (const float*)d_in[6];
  const float* W_hh0  = (const float*)d_in[7];
  const float* b_ih0  = (const float*)d_in[8];
  const float* b_hh0  = (const float*)d_in[9];
  const float* W_ih1  = (const float*)d_in[10];
  const float* W_hh1  = (const float*)d_in[11];
  const float* b_ih1  = (const float*)d_in[12];
  const float* b_hh1  = (const float*)d_in[13];
  const float* W_out  = (const float*)d_in[14];
  const float* b_out  = (const float*)d_in[15];
  float* out = (float*)d_out;

  // ---- workspace carve (~74 MB) ----
  char* p = (char*)d_ws;
  auto alloc = [&](size_t bytes) { void* r = p; p += (bytes + 255) & ~(size_t)255; return r; };
  short* woutB = (short*)alloc(32000ULL * 1024 * 2);
  short* catB  = (short*)alloc(2048ULL * 1024 * 2);
  float* encP  = (float*)alloc(2048ULL * 512 * 4);
  float* ctx   = (float*)alloc(32ULL * 512 * 4);
  float* st    = (float*)alloc(8ULL * 16384 * 4);
  unsigned* bar = (unsigned*)alloc(16384);
  float* h0b = st, *h1b = st + 2 * 16384, *c0b = st + 4 * 16384, *c1b = st + 6 * 16384;

  // ---- prep ----
  hipLaunchKernelGGL(cvt_bf16_k, dim3(4096), dim3(256), 0, stream, W_out, woutB, 32000L * 1024);
  // encP = enc @ W_a in FP32 (recurrence-critical precision)
  hipLaunchKernelGGL(gemm_f32_k, dim3(8, 32), dim3(256), 0, stream,
                     enc, W_a, encP, 2048, 512, 512, 512);
  hipLaunchKernelGGL(init_states_k, dim3(64), dim3(256), 0, stream, hidden, cell,
                     h0b, h1b, c0b, c1b, bar);

  // ---- recurrence: ONE persistent kernel, 64 steps, 3 relaxed gbar/step ----
  {
    int occ = 0;
    hipError_t e = hipOccupancyMaxActiveBlocksPerMultiprocessor(
        &occ, (const void*)decode_loop_k, 256, 0);
    int nblocks = (e == hipSuccess && occ >= 2) ? 512 : 256;
    hipLaunchKernelGGL(decode_loop_k, dim3(nblocks), dim3(256), 0, stream,
                       tgt, emb, enc, encP,
                       W_ih0, W_hh0, b_ih0, b_hh0,
                       W_ih1, W_hh1, b_ih1, b_hh1,
                       ctx, st, catB, bar);
  }

  // ---- final states (after t=63, new state sits in ping-pong slot 0) ----
  hipLaunchKernelGGL(fin_states_k, dim3(64), dim3(256), 0, stream,
                     h0b, h1b, c0b, c1b, out + 65536000L);

  // ---- output projection: [2048x1024] @ [1024x32000] + b_out ----
  hipLaunchKernelGGL(gemm_bf16, dim3(250, 16), dim3(256), 0, stream,
                     catB, woutB, out, b_out,
                     2048, 32000, 1024, 1024, 1024, 32000);
}